// Round 5
// baseline (255.805 us; speedup 1.0000x reference)
//
#include <hip/hip_runtime.h>
#include <hip/hip_bf16.h>
#include <stdint.h>

#define B_   4
#define C_   128
#define H_   128
#define W_   128
#define O_   128
#define HW_  16384
#define KK   9
#define KD   1152          // C_*KK
#define TM   32            // pixels per block
#define PS_LD 1160         // 1152 + 8 pad (16B) -> 2-way bank alias only

typedef float f32x4 __attribute__((ext_vector_type(4)));
typedef short s16x8 __attribute__((ext_vector_type(8)));

__device__ __forceinline__ uint32_t f2bf(float f) {
  uint32_t u = __builtin_bit_cast(uint32_t, f);
  u += 0x7FFFu + ((u >> 16) & 1u);   // RNE
  return u >> 16;
}
__device__ __forceinline__ float bflo(uint32_t v) { return __builtin_bit_cast(float, v << 16); }
__device__ __forceinline__ float bfhi(uint32_t v) { return __builtin_bit_cast(float, v & 0xFFFF0000u); }

// ---------------- x: (B,C,H,W) f32 -> (B,HW,C) bf16 ----------------
__global__ __launch_bounds__(256) void k_transpose(const float* __restrict__ x,
                                                   uint16_t* __restrict__ xt) {
  __shared__ float t[32][33];
  int tid = threadIdx.x;
  int bx  = blockIdx.x;            // b*512 + hw-tile
  int b   = bx >> 9;
  int hw0 = (bx & 511) << 5;
  int c0  = blockIdx.y << 5;
  int tx = tid & 31, ty = tid >> 5;
#pragma unroll
  for (int i = 0; i < 4; ++i) {
    int c = c0 + ty + (i << 3);
    t[ty + (i << 3)][tx] = x[(b * C_ + c) * HW_ + hw0 + tx];
  }
  __syncthreads();
#pragma unroll
  for (int r = 0; r < 2; ++r) {
    int u   = tid + (r << 8);
    int hwl = u >> 4;
    int cp  = (u & 15) << 1;
    uint32_t pack = f2bf(t[cp][hwl]) | (f2bf(t[cp + 1][hwl]) << 16);
    *reinterpret_cast<uint32_t*>(xt + ((b * HW_ + hw0 + hwl) * C_ + c0 + cp)) = pack;
  }
}

// ---------------- weight: (O,C,3,3) f32 -> wT[o][kpos*128+c] bf16 ----------------
__global__ __launch_bounds__(256) void k_weight(const float* __restrict__ w,
                                                uint16_t* __restrict__ wt) {
  int g = blockIdx.x * 256 + threadIdx.x;        // 147456 total
  int o   = g / KD;
  int rem = g - o * KD;
  int kp  = rem >> 7;
  int c   = rem & 127;
  wt[g] = (uint16_t)f2bf(w[(o * C_ + c) * KK + kp]);
}

// ---------------- main: interp -> LDS -> MFMA -> coalesced store ----------------
__global__ __launch_bounds__(512, 4) void k_main(const float* __restrict__ off,
                                                 const uint16_t* __restrict__ xt,
                                                 const uint16_t* __restrict__ wt,
                                                 float* __restrict__ out) {
  __shared__ __align__(16) unsigned char smem[TM * PS_LD * 2];
  uint16_t (*ps)[PS_LD] = reinterpret_cast<uint16_t(*)[PS_LD]>(smem);

  int tid  = threadIdx.x;
  int lane = tid & 63, wv = tid >> 6;
  int p0   = blockIdx.x * TM;
  int b    = p0 >> 14;
  int hw0  = p0 & (HW_ - 1);

  // ---- Phase A: bilinear interpolation into LDS patches ----
  {
    int c0 = lane << 1;
    const uint16_t* base = xt + (b * HW_) * C_ + c0;
    for (int task = wv; task < TM * KK; task += 8) {
      int pix = task / 9;
      int k   = task - pix * 9;
      int hw  = hw0 + pix;
      int h = hw >> 7, w = hw & 127;
      float oy = off[(b * 18 + 2 * k) * HW_ + hw];
      float ox = off[(b * 18 + 2 * k + 1) * HW_ + hw];
      int kdy = k / 3;
      int kdx = k - 3 * kdy;
      float py = (float)(h + kdy - 1) + oy;
      float px = (float)(w + kdx - 1) + ox;
      float yf = floorf(py), xf = floorf(px);
      int y0 = (int)yf, x0 = (int)xf;
      float wy = py - yf, wx = px - xf;

      auto LD = [&](int y, int x) -> uint32_t {
        if ((unsigned)y < (unsigned)H_ && (unsigned)x < (unsigned)W_)
          return *reinterpret_cast<const uint32_t*>(base + (y * W_ + x) * C_);
        return 0u;
      };
      uint32_t g00 = LD(y0, x0),     g01 = LD(y0, x0 + 1);
      uint32_t g10 = LD(y0 + 1, x0), g11 = LD(y0 + 1, x0 + 1);

      float w00 = (1.f - wy) * (1.f - wx), w01 = (1.f - wy) * wx;
      float w10 = wy * (1.f - wx),         w11 = wy * wx;
      float lo = w00 * bflo(g00) + w01 * bflo(g01) + w10 * bflo(g10) + w11 * bflo(g11);
      float hi = w00 * bfhi(g00) + w01 * bfhi(g01) + w10 * bfhi(g10) + w11 * bfhi(g11);
      *reinterpret_cast<uint32_t*>(&ps[pix][(k << 7) + c0]) = f2bf(lo) | (f2bf(hi) << 16);
    }
  }
  __syncthreads();

  // ---- Phase B: GEMM. wave wv -> outch [16*wv, 16*wv+16), 32 pixels ----
  f32x4 acc0 = {0.f, 0.f, 0.f, 0.f}, acc1 = {0.f, 0.f, 0.f, 0.f};
  {
    int r = lane & 15, g = lane >> 4;
    const uint16_t* wrow = wt + (wv * 16 + r) * KD + g * 8;
    const uint16_t* a0p  = &ps[r][g * 8];
    const uint16_t* a1p  = &ps[16 + r][g * 8];
#pragma unroll
    for (int s = 0; s < 36; ++s) {
      s16x8 bf = *reinterpret_cast<const s16x8*>(wrow + s * 32);
      s16x8 a0 = *reinterpret_cast<const s16x8*>(a0p + s * 32);
      s16x8 a1 = *reinterpret_cast<const s16x8*>(a1p + s * 32);
      acc0 = __builtin_amdgcn_mfma_f32_16x16x32_bf16(a0, bf, acc0, 0, 0, 0);
      acc1 = __builtin_amdgcn_mfma_f32_16x16x32_bf16(a1, bf, acc1, 0, 0, 0);
    }
  }
  __syncthreads();

  // ---- Phase C: accumulators -> LDS [128][33] f32 -> coalesced global store ----
  float* lout = reinterpret_cast<float*>(smem);
  {
    int r = lane & 15, g = lane >> 4;
    int o = wv * 16 + r;
#pragma unroll
    for (int i = 0; i < 4; ++i) lout[o * 33 + (g << 2) + i] = acc0[i];
#pragma unroll
    for (int i = 0; i < 4; ++i) lout[o * 33 + 16 + (g << 2) + i] = acc1[i];
  }
  __syncthreads();
  {
    int pl = tid & 31, og = tid >> 5;
    float* obase = out + (b * O_) * HW_ + hw0 + pl;
#pragma unroll
    for (int i = 0; i < 8; ++i) {
      int o = og * 8 + i;
      obase[o * HW_] = lout[o * 33 + pl];
    }
  }
}

extern "C" void kernel_launch(void* const* d_in, const int* in_sizes, int n_in,
                              void* d_out, int out_size, void* d_ws, size_t ws_size,
                              hipStream_t stream) {
  const float* x   = (const float*)d_in[0];
  const float* off = (const float*)d_in[1];
  const float* wgt = (const float*)d_in[2];
  float* out = (float*)d_out;

  uint16_t* xt = (uint16_t*)d_ws;                      // 8,388,608 bf16 = 16 MB
  uint16_t* wt = xt + (size_t)B_ * HW_ * C_;           // 147,456 bf16 = 288 KB

  k_transpose<<<dim3(2048, 4), 256, 0, stream>>>(x, xt);
  k_weight<<<576, 256, 0, stream>>>(wgt, wt);
  k_main<<<2048, 512, 0, stream>>>(off, xt, wt, out);
}

// Round 11
// 184.741 us; speedup vs baseline: 1.3847x; 1.3847x over previous
//
#include <hip/hip_runtime.h>
#include <hip/hip_bf16.h>
#include <stdint.h>

#define B_   4
#define C_   128
#define H_   128
#define W_   128
#define O_   128
#define HW_  16384
#define KK   9
#define KD   1152          // C_*KK
#define TM   32            // pixels per block
#define PS_LD 1160         // 1152 + 8 pad elements

typedef float f32x4 __attribute__((ext_vector_type(4)));
typedef short s16x8 __attribute__((ext_vector_type(8)));
typedef uint32_t u32x4 __attribute__((ext_vector_type(4)));

__device__ __forceinline__ uint32_t f2bf(float f) {
  uint32_t u = __builtin_bit_cast(uint32_t, f);
  u += 0x7FFFu + ((u >> 16) & 1u);   // RNE
  return u >> 16;
}
__device__ __forceinline__ float bflo(uint32_t v) { return __builtin_bit_cast(float, v << 16); }
__device__ __forceinline__ float bfhi(uint32_t v) { return __builtin_bit_cast(float, v & 0xFFFF0000u); }
__device__ __forceinline__ uint32_t pk2bf(float lo, float hi) {
  return f2bf(lo) | (f2bf(hi) << 16);   // RNE pair pack, trivially-copyable types only
}

// ---------------- x: (B,C,H,W) f32 -> (B,HW,C) bf16 (vectorized) ----------------
// tile = 64 c x 64 hw; 2048 blocks x 256 thr
__global__ __launch_bounds__(256) void k_transpose(const float* __restrict__ x,
                                                   uint16_t* __restrict__ xt) {
  __shared__ uint32_t upk[64][33];   // [hw_local][c-pair], pad 33 -> 2-way max
  int tid = threadIdx.x;
  int bid = blockIdx.x;
  int b   = bid >> 9;                // 512 tiles per batch
  int r   = bid & 511;
  int c0  = (r >> 8) << 6;           // 0 or 64
  int hw0 = (r & 255) << 6;

#pragma unroll
  for (int p = 0; p < 2; ++p) {
    int cp = p * 16 + (tid >> 4);          // c-pair local 0..31
    int c  = c0 + (cp << 1);
    int hw = (tid & 15) << 2;
    const float* s0 = x + ((size_t)(b * C_ + c) * HW_) + hw0 + hw;
    f32x4 v0 = *reinterpret_cast<const f32x4*>(s0);
    f32x4 v1 = *reinterpret_cast<const f32x4*>(s0 + HW_);
#pragma unroll
    for (int q = 0; q < 4; ++q)
      upk[hw + q][cp] = pk2bf(v0[q], v1[q]);
  }
  __syncthreads();
#pragma unroll
  for (int p = 0; p < 2; ++p) {
    int hwl = p * 32 + (tid >> 3);
    int j   = tid & 7;                      // c-pair group
    u32x4 o;
#pragma unroll
    for (int i = 0; i < 4; ++i) o[i] = upk[hwl][j * 4 + i];
    *reinterpret_cast<u32x4*>(xt + ((size_t)(b * HW_ + hw0 + hwl) * C_) + c0 + j * 8) = o;
  }
}

// ---------------- weight: (O,C,3,3) f32 -> wT[o][kpos*128+c] bf16 ----------------
__global__ __launch_bounds__(256) void k_weight(const float* __restrict__ w,
                                                uint16_t* __restrict__ wt) {
  int g = blockIdx.x * 256 + threadIdx.x;        // 147456 total
  int o   = g / KD;
  int rem = g - o * KD;
  int kp  = rem >> 7;
  int c   = rem & 127;
  wt[g] = (uint16_t)f2bf(w[(o * C_ + c) * KK + kp]);
}

// ---------------- main: interp -> LDS -> MFMA -> coalesced store ----------------
__global__ __launch_bounds__(512, 4) void k_main(const float* __restrict__ off,
                                                 const uint16_t* __restrict__ xt,
                                                 const uint16_t* __restrict__ wt,
                                                 float* __restrict__ out) {
  __shared__ __align__(16) unsigned char smem[TM * PS_LD * 2];
  uint16_t (*ps)[PS_LD] = reinterpret_cast<uint16_t(*)[PS_LD]>(smem);

  int tid  = threadIdx.x;
  int lane = tid & 63, wv = tid >> 6;

  // XCD-aware bijective swizzle (2048 % 8 == 0)
  int sbid = ((blockIdx.x & 7) << 8) + (blockIdx.x >> 3);
  int p0   = sbid * TM;
  int b    = p0 >> 14;
  int hw0  = p0 & (HW_ - 1);

  // ---- Phase A: 16 lanes/tap, 8 ch/lane, 9 unrolled taps, 4 pixels/wave ----
  {
    int q  = lane >> 4;                 // quarter -> pixel
    int j  = lane & 15;                 // 8-channel group
    int pix = (wv << 2) + q;            // 0..31
    int hw  = hw0 + pix;
    int h = hw >> 7, w = hw & 127;
    int c0 = j << 3;
    const uint16_t* bbase = xt + (size_t)b * HW_ * C_ + c0;
    const float*    offb  = off + (size_t)b * 18 * HW_ + hw;
    uint16_t*       psW   = &ps[pix][c0];

#pragma unroll
    for (int k = 0; k < KK; ++k) {
      const int kdy = k / 3 - 1, kdx = k % 3 - 1;
      float oy = offb[(2 * k) * HW_];
      float ox = offb[(2 * k + 1) * HW_];
      float py = (float)(h + kdy) + oy;
      float px = (float)(w + kdx) + ox;
      float yf = floorf(py), xf = floorf(px);
      float wy = py - yf, wx = px - xf;
      int y0 = (int)yf, x0 = (int)xf;
      int y1 = y0 + 1, x1 = x0 + 1;
      int y0c = min(max(y0, 0), H_ - 1), y1c = min(max(y1, 0), H_ - 1);
      int x0c = min(max(x0, 0), W_ - 1), x1c = min(max(x1, 0), W_ - 1);
      bool vy0 = (unsigned)y0 < (unsigned)H_, vy1 = (unsigned)y1 < (unsigned)H_;
      bool vx0 = (unsigned)x0 < (unsigned)W_, vx1 = (unsigned)x1 < (unsigned)W_;
      float ay = 1.f - wy, ax = 1.f - wx;
      float w00 = (vy0 && vx0) ? ay * ax : 0.f;
      float w01 = (vy0 && vx1) ? ay * wx : 0.f;
      float w10 = (vy1 && vx0) ? wy * ax : 0.f;
      float w11 = (vy1 && vx1) ? wy * wx : 0.f;

      u32x4 g00 = *reinterpret_cast<const u32x4*>(bbase + (((y0c << 7) + x0c) << 7));
      u32x4 g01 = *reinterpret_cast<const u32x4*>(bbase + (((y0c << 7) + x1c) << 7));
      u32x4 g10 = *reinterpret_cast<const u32x4*>(bbase + (((y1c << 7) + x0c) << 7));
      u32x4 g11 = *reinterpret_cast<const u32x4*>(bbase + (((y1c << 7) + x1c) << 7));

      u32x4 outv;
#pragma unroll
      for (int i = 0; i < 4; ++i) {
        float lo = w00 * bflo(g00[i]) + w01 * bflo(g01[i]) + w10 * bflo(g10[i]) + w11 * bflo(g11[i]);
        float hi = w00 * bfhi(g00[i]) + w01 * bfhi(g01[i]) + w10 * bfhi(g10[i]) + w11 * bfhi(g11[i]);
        outv[i] = pk2bf(lo, hi);
      }
      *reinterpret_cast<u32x4*>(psW + (k << 7)) = outv;
    }
  }
  __syncthreads();

  // ---- Phase B: GEMM. wave wv -> outch [16*wv, 16*wv+16), 32 pixels ----
  f32x4 acc0 = {0.f, 0.f, 0.f, 0.f}, acc1 = {0.f, 0.f, 0.f, 0.f};
  {
    int r = lane & 15, g = lane >> 4;
    const uint16_t* wrow = wt + (wv * 16 + r) * KD + g * 8;
    const uint16_t* a0p  = &ps[r][g * 8];
    const uint16_t* a1p  = &ps[16 + r][g * 8];
#pragma unroll
    for (int s = 0; s < 36; ++s) {
      s16x8 bf = *reinterpret_cast<const s16x8*>(wrow + s * 32);
      s16x8 a0 = *reinterpret_cast<const s16x8*>(a0p + s * 32);
      s16x8 a1 = *reinterpret_cast<const s16x8*>(a1p + s * 32);
      acc0 = __builtin_amdgcn_mfma_f32_16x16x32_bf16(a0, bf, acc0, 0, 0, 0);
      acc1 = __builtin_amdgcn_mfma_f32_16x16x32_bf16(a1, bf, acc1, 0, 0, 0);
    }
  }
  __syncthreads();

  // ---- Phase C: accumulators -> LDS [128][33] f32 -> coalesced global store ----
  float* lout = reinterpret_cast<float*>(smem);
  {
    int r = lane & 15, g = lane >> 4;
    int o = wv * 16 + r;
#pragma unroll
    for (int i = 0; i < 4; ++i) lout[o * 33 + (g << 2) + i] = acc0[i];
#pragma unroll
    for (int i = 0; i < 4; ++i) lout[o * 33 + 16 + (g << 2) + i] = acc1[i];
  }
  __syncthreads();
  {
    int pl = tid & 31, og = tid >> 5;
    float* obase = out + (b * O_) * HW_ + hw0 + pl;
#pragma unroll
    for (int i = 0; i < 8; ++i) {
      int o = og * 8 + i;
      obase[o * HW_] = lout[o * 33 + pl];
    }
  }
}

extern "C" void kernel_launch(void* const* d_in, const int* in_sizes, int n_in,
                              void* d_out, int out_size, void* d_ws, size_t ws_size,
                              hipStream_t stream) {
  const float* x   = (const float*)d_in[0];
  const float* off = (const float*)d_in[1];
  const float* wgt = (const float*)d_in[2];
  float* out = (float*)d_out;

  uint16_t* xt = (uint16_t*)d_ws;                      // 8,388,608 bf16 = 16 MB
  uint16_t* wt = xt + (size_t)B_ * HW_ * C_;           // 147,456 bf16 = 288 KB

  k_transpose<<<2048, 256, 0, stream>>>(x, xt);
  k_weight<<<576, 256, 0, stream>>>(wgt, wt);
  k_main<<<2048, 512, 0, stream>>>(off, xt, wt, out);
}

// Round 13
// 176.455 us; speedup vs baseline: 1.4497x; 1.0470x over previous
//
#include <hip/hip_runtime.h>
#include <hip/hip_bf16.h>
#include <stdint.h>

#define B_   4
#define C_   128
#define H_   128
#define W_   128
#define O_   128
#define HW_  16384
#define KK   9
#define KD   1152          // C_*KK
#define TM   32            // pixels per block
#define CLD  136           // 128 + 8 pad elems per pixel-row per chunk

typedef float f32x4 __attribute__((ext_vector_type(4)));
typedef short s16x8 __attribute__((ext_vector_type(8)));
typedef uint32_t u32x4 __attribute__((ext_vector_type(4)));

__device__ __forceinline__ uint32_t f2bf(float f) {
  uint32_t u = __builtin_bit_cast(uint32_t, f);
  u += 0x7FFFu + ((u >> 16) & 1u);   // RNE
  return u >> 16;
}
__device__ __forceinline__ float bflo(uint32_t v) { return __builtin_bit_cast(float, v << 16); }
__device__ __forceinline__ float bfhi(uint32_t v) { return __builtin_bit_cast(float, v & 0xFFFF0000u); }
__device__ __forceinline__ uint32_t pk2bf(float lo, float hi) {
  return f2bf(lo) | (f2bf(hi) << 16);
}

// ---------------- x: (B,C,H,W) f32 -> (B,HW,C) bf16 (vectorized) ----------------
__global__ __launch_bounds__(256) void k_transpose(const float* __restrict__ x,
                                                   uint16_t* __restrict__ xt) {
  __shared__ uint32_t upk[64][33];
  int tid = threadIdx.x;
  int bid = blockIdx.x;
  int b   = bid >> 9;
  int r   = bid & 511;
  int c0  = (r >> 8) << 6;
  int hw0 = (r & 255) << 6;

#pragma unroll
  for (int p = 0; p < 2; ++p) {
    int cp = p * 16 + (tid >> 4);
    int c  = c0 + (cp << 1);
    int hw = (tid & 15) << 2;
    const float* s0 = x + ((size_t)(b * C_ + c) * HW_) + hw0 + hw;
    f32x4 v0 = *reinterpret_cast<const f32x4*>(s0);
    f32x4 v1 = *reinterpret_cast<const f32x4*>(s0 + HW_);
#pragma unroll
    for (int qq = 0; qq < 4; ++qq)
      upk[hw + qq][cp] = pk2bf(v0[qq], v1[qq]);
  }
  __syncthreads();
#pragma unroll
  for (int p = 0; p < 2; ++p) {
    int hwl = p * 32 + (tid >> 3);
    int jj  = tid & 7;
    u32x4 o;
#pragma unroll
    for (int i = 0; i < 4; ++i) o[i] = upk[hwl][jj * 4 + i];
    *reinterpret_cast<u32x4*>(xt + ((size_t)(b * HW_ + hw0 + hwl) * C_) + c0 + jj * 8) = o;
  }
}

// ---------------- weight: (O,C,3,3) f32 -> wT[o][kpos*128+c] bf16 ----------------
__global__ __launch_bounds__(256) void k_weight(const float* __restrict__ w,
                                                uint16_t* __restrict__ wt) {
  int gg = blockIdx.x * 256 + threadIdx.x;
  int o   = gg / KD;
  int rem = gg - o * KD;
  int kp  = rem >> 7;
  int c   = rem & 127;
  wt[gg] = (uint16_t)f2bf(w[(o * C_ + c) * KK + kp]);
}

// ---------------- main: 9-chunk double-buffered interp||MFMA pipeline ----------------
__global__ __launch_bounds__(512, 8) void k_main(const float* __restrict__ off,
                                                 const uint16_t* __restrict__ xt,
                                                 const uint16_t* __restrict__ wt,
                                                 float* __restrict__ out) {
  __shared__ __align__(16) uint16_t ps2[2][TM][CLD];   // 17,408 B -> 4 blocks/CU
  int tid  = threadIdx.x;
  int lane = tid & 63, wv = tid >> 6;

  int sbid = ((blockIdx.x & 7) << 8) | (blockIdx.x >> 3);   // XCD swizzle, bijective
  int p0   = sbid * TM;
  int b    = p0 >> 14;
  int hw0  = p0 & (HW_ - 1);

  // Phase-A roles: quarter q -> pixel, j -> 8-channel group
  int q   = lane >> 4;
  int j   = lane & 15;
  int pix = (wv << 2) + q;
  int hw  = hw0 + pix;
  int h = hw >> 7, w = hw & 127;
  uint32_t cb = (uint32_t)(j << 4);                 // channel-group byte offset
  const char*  xtb  = (const char*)(xt + (size_t)b * HW_ * C_);
  const float* offb = off + (size_t)b * 18 * HW_ + hw;

  // Phase-B roles: r -> outch within wave's 16, g -> K-group
  int r = lane & 15, g = lane >> 4;
  const uint16_t* wrow = wt + (wv * 16 + r) * KD + g * 8;

  f32x4 acc0 = {0.f,0.f,0.f,0.f}, acc1 = {0.f,0.f,0.f,0.f};

  float oyv[9], oxv[9];
  u32x4 g0, g1, g2, g3;
  float w00, w01, w10, w11;

#define GATHER_TAP(K)                                                          \
  {                                                                            \
    const int kdy = (K)/3 - 1, kdx = (K)%3 - 1;                                \
    float py = (float)(h + kdy) + oyv[K];                                      \
    float px = (float)(w + kdx) + oxv[K];                                      \
    float yf = floorf(py), xf = floorf(px);                                    \
    float wy = py - yf, wx = px - xf;                                          \
    int y0 = (int)yf, x0 = (int)xf;                                            \
    int y1 = y0 + 1, x1 = x0 + 1;                                              \
    int y0c = min(max(y0,0),H_-1), y1c = min(max(y1,0),H_-1);                  \
    int x0c = min(max(x0,0),W_-1), x1c = min(max(x1,0),W_-1);                  \
    bool vy0 = (unsigned)y0 < (unsigned)H_, vy1 = (unsigned)y1 < (unsigned)H_; \
    bool vx0 = (unsigned)x0 < (unsigned)W_, vx1 = (unsigned)x1 < (unsigned)W_; \
    float ay = 1.f - wy, ax = 1.f - wx;                                        \
    w00 = (vy0 && vx0) ? ay*ax : 0.f;                                          \
    w01 = (vy0 && vx1) ? ay*wx : 0.f;                                          \
    w10 = (vy1 && vx0) ? wy*ax : 0.f;                                          \
    w11 = (vy1 && vx1) ? wy*wx : 0.f;                                          \
    uint32_t o00 = ((uint32_t)((y0c<<7)+x0c)<<8) + cb;                         \
    uint32_t o01 = ((uint32_t)((y0c<<7)+x1c)<<8) + cb;                         \
    uint32_t o10 = ((uint32_t)((y1c<<7)+x0c)<<8) + cb;                         \
    uint32_t o11 = ((uint32_t)((y1c<<7)+x1c)<<8) + cb;                         \
    g0 = *reinterpret_cast<const u32x4*>(xtb + o00);                           \
    g1 = *reinterpret_cast<const u32x4*>(xtb + o01);                           \
    g2 = *reinterpret_cast<const u32x4*>(xtb + o10);                           \
    g3 = *reinterpret_cast<const u32x4*>(xtb + o11);                           \
  }

#define INTERP_TAP(BUF)                                                        \
  {                                                                            \
    u32x4 ov;                                                                  \
    _Pragma("unroll")                                                          \
    for (int i = 0; i < 4; ++i) {                                              \
      float lo = w00*bflo(g0[i]) + w01*bflo(g1[i]) + w10*bflo(g2[i]) + w11*bflo(g3[i]); \
      float hi = w00*bfhi(g0[i]) + w01*bfhi(g1[i]) + w10*bfhi(g2[i]) + w11*bfhi(g3[i]); \
      ov[i] = pk2bf(lo, hi);                                                   \
    }                                                                          \
    *reinterpret_cast<u32x4*>(&ps2[BUF][pix][j*8]) = ov;                       \
  }

  // prologue: offsets for taps 0..2; tap 0 staged into buf 0
  oyv[0] = offb[0];        oxv[0] = offb[HW_];
  oyv[1] = offb[2*HW_];    oxv[1] = offb[3*HW_];
  oyv[2] = offb[4*HW_];    oxv[2] = offb[5*HW_];
  GATHER_TAP(0);
  INTERP_TAP(0);
  __syncthreads();

#pragma unroll
  for (int k = 0; k < 9; ++k) {
    if (k < 8) GATHER_TAP(k+1);                     // issue next tap's gathers early
    if (k < 6) {                                    // offsets 3 taps ahead
      oyv[k+3] = offb[(2*(k+3))*HW_];
      oxv[k+3] = offb[(2*(k+3)+1)*HW_];
    }
    {                                               // MFMA on chunk k (buf k&1)
      const uint16_t* b0 = &ps2[k&1][r][g*8];
      const uint16_t* b1 = &ps2[k&1][16+r][g*8];
#pragma unroll
      for (int s = 0; s < 4; ++s) {
        s16x8 bfv = *reinterpret_cast<const s16x8*>(wrow + (k*4+s)*32);
        s16x8 a0  = *reinterpret_cast<const s16x8*>(b0 + s*32);
        s16x8 a1  = *reinterpret_cast<const s16x8*>(b1 + s*32);
        acc0 = __builtin_amdgcn_mfma_f32_16x16x32_bf16(a0, bfv, acc0, 0,0,0);
        acc1 = __builtin_amdgcn_mfma_f32_16x16x32_bf16(a1, bfv, acc1, 0,0,0);
      }
    }
    if (k < 8) INTERP_TAP((k+1)&1);                 // finish next tap into other buf
    __syncthreads();
  }

  // ---- Phase C: accumulators -> LDS (reuse ps2) -> coalesced store ----
  float* lout = reinterpret_cast<float*>(&ps2[0][0][0]);  // 128*33*4 = 16,896 B <= 17,408
  {
    int o = wv * 16 + r;
#pragma unroll
    for (int i = 0; i < 4; ++i) lout[o * 33 + (g << 2) + i] = acc0[i];
#pragma unroll
    for (int i = 0; i < 4; ++i) lout[o * 33 + 16 + (g << 2) + i] = acc1[i];
  }
  __syncthreads();
  {
    int pl = tid & 31, og = tid >> 5;
    float* obase = out + (size_t)(b * O_) * HW_ + hw0 + pl;
#pragma unroll
    for (int i = 0; i < 8; ++i) {
      int o = og * 8 + i;
      obase[(size_t)o * HW_] = lout[o * 33 + pl];
    }
  }
#undef GATHER_TAP
#undef INTERP_TAP
}

extern "C" void kernel_launch(void* const* d_in, const int* in_sizes, int n_in,
                              void* d_out, int out_size, void* d_ws, size_t ws_size,
                              hipStream_t stream) {
  const float* x   = (const float*)d_in[0];
  const float* off = (const float*)d_in[1];
  const float* wgt = (const float*)d_in[2];
  float* out = (float*)d_out;

  uint16_t* xt = (uint16_t*)d_ws;                      // 16 MB
  uint16_t* wt = xt + (size_t)B_ * HW_ * C_;           // 288 KB

  k_transpose<<<2048, 256, 0, stream>>>(x, xt);
  k_weight<<<576, 256, 0, stream>>>(wgt, wt);
  k_main<<<2048, 512, 0, stream>>>(off, xt, wt, out);
}